// Round 2
// baseline (14650.618 us; speedup 1.0000x reference)
//
#include <hip/hip_runtime.h>
#include <hip/hip_bf16.h>

#define UNITS 1024
#define FEAT  16
#define TSTEPS 512
#define OUTSTEPS 24
#define BATCH 256
#define KTOT  1088   // 16 (x) + 1024 (h) + 48 pad
#define NROWS 4096   // 4*UNITS, reordered r = 4*u + gate

typedef __bf16 bf16x8 __attribute__((ext_vector_type(8)));
typedef float  f32x4  __attribute__((ext_vector_type(4)));

__device__ __forceinline__ float sigmoidf_(float x) { return 1.f / (1.f + __expf(-x)); }
__device__ __forceinline__ float tanhf_(float x)    { return 1.f - 2.f / (__expf(2.f * x) + 1.f); }

// ---------------------------------------------------------------------------
// Build Wcat_T[r][k] (bf16, row-major, stride KTOT), r = 4*u + g -> orig col
// c = g*1024 + u.  k<16: kernel[k][c]; 16<=k<1040: rec_kernel[k-16][c]; else 0.
// ---------------------------------------------------------------------------
__global__ __launch_bounds__(256) void prep_weights(const float* __restrict__ kern,
                                                    const float* __restrict__ rec,
                                                    __bf16* __restrict__ Wcat) {
    __shared__ __align__(16) __bf16 tile[64][72];
    int r0 = blockIdx.x * 64;          // 64 r-tiles
    int k0 = blockIdx.y * 64;          // 17 k-tiles
    int t  = threadIdx.x;
    int c_off = t & 63;                // which of the 64 r's (as (g,ui))
    int k_grp = t >> 6;                // 0..3, 16 k's each
    int g = c_off >> 4, ui = c_off & 15;
    int u0 = r0 >> 2;
    int c  = g * 1024 + u0 + ui;       // original column in (F/U x 4096) weights
    int rl = 4 * ui + g;               // local r
    for (int i = 0; i < 16; i++) {
        int k = k0 + k_grp * 16 + i;
        float v = 0.f;
        if (k < 16)        v = kern[(size_t)k * NROWS + c];
        else if (k < 1040) v = rec[(size_t)(k - 16) * NROWS + c];
        tile[rl][k_grp * 16 + i] = (__bf16)v;
    }
    __syncthreads();
    int rl2 = t >> 2, ch = t & 3;      // write 16 cols per thread
    bf16x8* dst = (bf16x8*)(Wcat + (size_t)(r0 + rl2) * KTOT + k0 + ch * 16);
    const bf16x8* src = (const bf16x8*)&tile[rl2][ch * 16];
    dst[0] = src[0];
    dst[1] = src[1];
}

// ---------------------------------------------------------------------------
// Zero h32/c32 (contiguous, 2*BATCH*UNITS floats), zero both Abuf buffers,
// write x[:,0,:] into Abuf0 cols 0..15.
// ---------------------------------------------------------------------------
__global__ __launch_bounds__(256) void prep_state(const float* __restrict__ x,
                                                  __bf16* __restrict__ Ab0,
                                                  __bf16* __restrict__ Ab1,
                                                  float* __restrict__ hc) {
    int tid = blockIdx.x * 256 + threadIdx.x;
    int np  = gridDim.x * 256;
    for (int i = tid; i < 2 * BATCH * UNITS; i += np) hc[i] = 0.f;
    const int AB = BATCH * KTOT;  // 278528
    for (int i = tid; i < 2 * AB; i += np) {
        int which = (i < AB) ? 0 : 1;
        int p = i - which * AB;
        int col = p % KTOT;
        int m   = p / KTOT;
        __bf16 v = (__bf16)0.f;
        if (which == 0 && col < FEAT) v = (__bf16)x[(size_t)m * TSTEPS * FEAT + col];
        if (which == 0) Ab0[p] = v; else Ab1[p] = v;
    }
}

// ---------------------------------------------------------------------------
// One PLSTM step: z = Abuf_r @ Wcat^T (MFMA bf16), gates, phased update.
// Grid 256 blocks x 256 thr. BM=32 (batch), BN=128 (=32 units x 4 gates), BK=64.
// Writes h32/c32 (fp32) and new h (bf16) into Abuf_w cols 16..1039.
// Block (n_block==0) also stages next x into Abuf_w cols 0..15 (warm phase).
// ---------------------------------------------------------------------------
__global__ __launch_bounds__(256) void step_kernel(
    const __bf16* __restrict__ Wcat, const __bf16* __restrict__ Abuf_r,
    __bf16* __restrict__ Abuf_w, float* __restrict__ h32, float* __restrict__ c32,
    const float* __restrict__ bias, const float* __restrict__ period,
    const float* __restrict__ phase, const float* __restrict__ ratio,
    const float* __restrict__ tsrc, int tstride, int use_mask,
    const float* __restrict__ xnext, int xstride) {
    __shared__ __align__(16) __bf16 As[32][72];
    __shared__ __align__(16) __bf16 Bs[128][72];
    int b = blockIdx.x;
    int xcd = b & 7, ib = b >> 3;
    int n_block = xcd * 4 + (ib & 3);   // 0..31  (XCD-local N range for L2 reuse)
    int m_block = ib >> 2;              // 0..7
    int m0 = m_block * 32;
    int n0 = n_block * 128;
    int tid = threadIdx.x;
    int lane = tid & 63, wave = tid >> 6;
    int l16 = lane & 15, quad = lane >> 4;
    int wn0 = wave * 32;

    f32x4 acc[2][2] = {};
    int arow = tid >> 3;
    int ach  = (tid & 7) * 8;
    const __bf16* aptr = Abuf_r + (size_t)(m0 + arow) * KTOT + ach;
    const __bf16* bptr = Wcat + (size_t)(n0 + arow) * KTOT + ach;

    for (int kt = 0; kt < 17; kt++) {
        int kb = kt * 64;
        *(bf16x8*)&As[arow][ach] = *(const bf16x8*)(aptr + kb);
#pragma unroll
        for (int ii = 0; ii < 4; ii++) {
            *(bf16x8*)&Bs[arow + ii * 32][ach] =
                *(const bf16x8*)(bptr + (size_t)ii * 32 * KTOT + kb);
        }
        __syncthreads();
#pragma unroll
        for (int s = 0; s < 2; s++) {
            bf16x8 a0 = *(const bf16x8*)&As[l16][s * 32 + quad * 8];
            bf16x8 a1 = *(const bf16x8*)&As[16 + l16][s * 32 + quad * 8];
            bf16x8 b0 = *(const bf16x8*)&Bs[wn0 + l16][s * 32 + quad * 8];
            bf16x8 b1 = *(const bf16x8*)&Bs[wn0 + 16 + l16][s * 32 + quad * 8];
            acc[0][0] = __builtin_amdgcn_mfma_f32_16x16x32_bf16(a0, b0, acc[0][0], 0, 0, 0);
            acc[0][1] = __builtin_amdgcn_mfma_f32_16x16x32_bf16(a0, b1, acc[0][1], 0, 0, 0);
            acc[1][0] = __builtin_amdgcn_mfma_f32_16x16x32_bf16(a1, b0, acc[1][0], 0, 0, 0);
            acc[1][1] = __builtin_amdgcn_mfma_f32_16x16x32_bf16(a1, b1, acc[1][1], 0, 0, 0);
        }
        __syncthreads();
    }

    // Epilogue: C-layout col = lane&15 (-> r = 4u+g, so lane&3 == gate),
    // row = quad*4 + reg (-> batch m). 3 shuffles gather i,f,g,o per unit.
    int ublk0 = n_block * 32;
    bool wlane = ((lane & 3) == 0);
#pragma unroll
    for (int mt = 0; mt < 2; mt++) {
#pragma unroll
        for (int r = 0; r < 4; r++) {
            int m_loc = mt * 16 + quad * 4 + r;
            int mg = m0 + m_loc;
            float tv = 0.f;
            int keep = 0;
            if (wlane) {
                const float* row = tsrc + (size_t)mg * tstride;
                tv = row[0];
                if (use_mask) {
                    bool any = false;
#pragma unroll
                    for (int f = 0; f < FEAT; f++) any = any || (row[f] != -1.0f);
                    keep = any ? 0 : 1;
                }
            }
#pragma unroll
            for (int nt = 0; nt < 2; nt++) {
                float z = acc[mt][nt][r];
                int base = lane & ~3;
                float zi = __shfl(z, base);
                float zf = __shfl(z, base + 1);
                float zg = __shfl(z, base + 2);
                float zo = __shfl(z, base + 3);
                if (wlane) {
                    int u = ublk0 + ((wn0 + nt * 16 + l16) >> 2);
                    zi += bias[u];
                    zf += bias[UNITS + u];
                    zg += bias[2 * UNITS + u];
                    zo += bias[3 * UNITS + u];
                    float ig = sigmoidf_(zi), fg = sigmoidf_(zf), og = sigmoidf_(zo);
                    float gv = tanhf_(zg);
                    size_t off = (size_t)mg * UNITS + u;
                    float cp = c32[off], hp = h32[off];
                    float nc = fg * cp + ig * gv;
                    float nh = og * tanhf_(nc);
                    float per = period[u], ph = phase[u], ro = ratio[u];
                    float cr = fmodf(tv - ph, per);
                    cr = (cr < 0.f) ? cr + per : cr;
                    cr = cr / per;
                    float kup = 2.f * cr / ro;
                    float kk = (cr < ro) ? (2.f - kup) : (0.001f * cr);
                    kk = (cr < 0.5f * ro) ? kup : kk;
                    float ho = kk * nh + (1.f - kk) * hp;
                    float co = kk * nc + (1.f - kk) * cp;
                    if (keep) { ho = hp; co = cp; }
                    h32[off] = ho;
                    c32[off] = co;
                    Abuf_w[(size_t)mg * KTOT + 16 + u] = (__bf16)ho;
                }
            }
        }
    }
    // stage next-step x into the write buffer (warm phase only)
    if (xnext != nullptr && n_block == 0) {
        for (int idx = tid; idx < 32 * FEAT; idx += 256) {
            int row = idx >> 4, f = idx & 15;
            Abuf_w[(size_t)(m0 + row) * KTOT + f] =
                (__bf16)xnext[(size_t)(m0 + row) * xstride + f];
        }
    }
}

// ---------------------------------------------------------------------------
// Dense layer 1: a1 = tanh(h32 @ w1 + b1), (256x1024)@(1024x256).
// Grid 64 blocks x 256 thr; block does 4 batch rows.
// ---------------------------------------------------------------------------
__global__ __launch_bounds__(256) void dense1(const float* __restrict__ h32,
                                              const float* __restrict__ w1,
                                              const float* __restrict__ b1,
                                              float* __restrict__ a1) {
    int m0 = blockIdx.x * 4;
    int j = threadIdx.x;
    float a0 = 0.f, a1v = 0.f, a2 = 0.f, a3 = 0.f;
    for (int k = 0; k < UNITS; k++) {
        float w = w1[(size_t)k * 256 + j];
        a0 += h32[(size_t)(m0 + 0) * UNITS + k] * w;
        a1v += h32[(size_t)(m0 + 1) * UNITS + k] * w;
        a2 += h32[(size_t)(m0 + 2) * UNITS + k] * w;
        a3 += h32[(size_t)(m0 + 3) * UNITS + k] * w;
    }
    float bb = b1[j];
    a1[(size_t)(m0 + 0) * 256 + j] = tanhf_(a0 + bb);
    a1[(size_t)(m0 + 1) * 256 + j] = tanhf_(a1v + bb);
    a1[(size_t)(m0 + 2) * 256 + j] = tanhf_(a2 + bb);
    a1[(size_t)(m0 + 3) * 256 + j] = tanhf_(a3 + bb);
}

// ---------------------------------------------------------------------------
// Dense tail: L2,L3,L4 fused. Grid 32 blocks x 256 thr; block does 8 rows.
// Writes pred into d_out[:, s, :] and (bf16) into Abuf_x cols 0..15.
// ---------------------------------------------------------------------------
__global__ __launch_bounds__(256) void dense_tail(
    const float* __restrict__ a1, const float* __restrict__ w2, const float* __restrict__ b2,
    const float* __restrict__ w3, const float* __restrict__ b3, const float* __restrict__ wo,
    const float* __restrict__ bo, float* __restrict__ out, __bf16* __restrict__ Abuf_x, int s) {
    __shared__ float a1s[8][256];
    __shared__ float a2s[8][128];
    __shared__ float a3s[8][64];
    int m0 = blockIdx.x * 8;
    int t = threadIdx.x;
    for (int i = 0; i < 8; i++) {
        int idx = t + i * 256;
        int r = idx >> 8, c = idx & 255;
        a1s[r][c] = a1[(size_t)(m0 + r) * 256 + c];
    }
    __syncthreads();
    {   // L2: 256 -> 128
        int j = t & 127, rb = t >> 7;
        float acc[4] = {0.f, 0.f, 0.f, 0.f};
        for (int k = 0; k < 256; k++) {
            float w = w2[(size_t)k * 128 + j];
#pragma unroll
            for (int q = 0; q < 4; q++) acc[q] += a1s[rb * 4 + q][k] * w;
        }
        float bb = b2[j];
#pragma unroll
        for (int q = 0; q < 4; q++) a2s[rb * 4 + q][j] = tanhf_(acc[q] + bb);
    }
    __syncthreads();
    {   // L3: 128 -> 64
        int j = t & 63, rb = t >> 6;
        float acc[2] = {0.f, 0.f};
        for (int k = 0; k < 128; k++) {
            float w = w3[(size_t)k * 64 + j];
#pragma unroll
            for (int q = 0; q < 2; q++) acc[q] += a2s[rb * 2 + q][k] * w;
        }
        float bb = b3[j];
#pragma unroll
        for (int q = 0; q < 2; q++) a3s[rb * 2 + q][j] = tanhf_(acc[q] + bb);
    }
    __syncthreads();
    if (t < 128) {  // L4: 64 -> 16
        int j = t & 15, r = t >> 4;
        float acc = 0.f;
        for (int k = 0; k < 64; k++) acc += a3s[r][k] * wo[(size_t)k * 16 + j];
        float v = acc + bo[j];
        out[(size_t)(m0 + r) * (OUTSTEPS * FEAT) + s * FEAT + j] = v;
        Abuf_x[(size_t)(m0 + r) * KTOT + j] = (__bf16)v;
    }
}

// ---------------------------------------------------------------------------
extern "C" void kernel_launch(void* const* d_in, const int* in_sizes, int n_in,
                              void* d_out, int out_size, void* d_ws, size_t ws_size,
                              hipStream_t stream) {
    const float* x      = (const float*)d_in[0];
    const float* kern   = (const float*)d_in[1];
    const float* rec    = (const float*)d_in[2];
    const float* bias   = (const float*)d_in[3];
    const float* period = (const float*)d_in[4];
    const float* phase  = (const float*)d_in[5];
    const float* ratio  = (const float*)d_in[6];
    const float* w1 = (const float*)d_in[7];
    const float* b1 = (const float*)d_in[8];
    const float* w2 = (const float*)d_in[9];
    const float* b2 = (const float*)d_in[10];
    const float* w3 = (const float*)d_in[11];
    const float* b3 = (const float*)d_in[12];
    const float* wo = (const float*)d_in[13];
    const float* bo = (const float*)d_in[14];
    float* out = (float*)d_out;

    char* ws = (char*)d_ws;
    const size_t WCAT_B = (size_t)NROWS * KTOT * 2;        // 8,912,896
    const size_t AB_B   = (size_t)BATCH * KTOT * 2;        // 557,056
    __bf16* Wcat = (__bf16*)ws;
    __bf16* Ab0  = (__bf16*)(ws + WCAT_B);
    __bf16* Ab1  = (__bf16*)(ws + WCAT_B + AB_B);
    float*  h32  = (float*)(ws + WCAT_B + 2 * AB_B);
    float*  c32  = h32 + (size_t)BATCH * UNITS;
    float*  a1   = c32 + (size_t)BATCH * UNITS;

    prep_weights<<<dim3(64, 17), 256, 0, stream>>>(kern, rec, Wcat);
    prep_state<<<512, 256, 0, stream>>>(x, Ab0, Ab1, h32);

    int rp = 0;  // parity of the buffer the next step READS
    for (int t = 0; t < TSTEPS; t++) {
        const float* tsrc = x + (size_t)t * FEAT;
        const float* xn = (t < TSTEPS - 1) ? x + (size_t)(t + 1) * FEAT : nullptr;
        step_kernel<<<256, 256, 0, stream>>>(Wcat, rp ? Ab1 : Ab0, rp ? Ab0 : Ab1,
                                             h32, c32, bias, period, phase, ratio,
                                             tsrc, TSTEPS * FEAT, 1, xn, TSTEPS * FEAT);
        rp ^= 1;
    }
    for (int s = 0; s < OUTSTEPS; s++) {
        dense1<<<64, 256, 0, stream>>>(h32, w1, b1, a1);
        dense_tail<<<32, 256, 0, stream>>>(a1, w2, b2, w3, b3, wo, bo, out,
                                           rp ? Ab1 : Ab0, s);
        if (s < OUTSTEPS - 1) {
            const float* tsrc = out + (size_t)s * FEAT;
            step_kernel<<<256, 256, 0, stream>>>(Wcat, rp ? Ab1 : Ab0, rp ? Ab0 : Ab1,
                                                 h32, c32, bias, period, phase, ratio,
                                                 tsrc, OUTSTEPS * FEAT, 0, nullptr, 0);
            rp ^= 1;
        }
    }
}